// Round 9
// baseline (556.491 us; speedup 1.0000x reference)
//
#include <hip/hip_runtime.h>
#include <cstdint>

#define NN 50000
#define NE 640000
#define NG 128
#define HD 128
#define FN 64
#define FE 16
#define FL 200
#define FPOC 100
#define NSTACK 3
#define NBUCK 782   // ceil(NN/64)
#define BCAP 1536   // Poisson(819) +25 sigma; fixed graph => deterministic safe

typedef unsigned short ushort_t;
typedef short short8 __attribute__((ext_vector_type(8)));
typedef float f32x4 __attribute__((ext_vector_type(4)));

__device__ __forceinline__ ushort_t f2bf(float f) {
    unsigned u = __float_as_uint(f);
    unsigned r = (u + 0x7fffu + ((u >> 16) & 1u)) >> 16;
    return (ushort_t)r;
}
__device__ __forceinline__ float bf2f(ushort_t u) {
    return __uint_as_float(((unsigned)u) << 16);
}

// ---------------- CSR build (bucketed two-pass scatter) ----------------
// Round-8 fill_kernel wrote 43MB for a 5.1MB payload (random 8B stores dirty a
// 64B sector each). Pass A appends edges densely into 64-node dst buckets;
// pass B scatters within one bucket's ~6.5KB csr range (cache-resident).

__global__ void countbucket_kernel(const int* __restrict__ ei, int* __restrict__ cnt,
                                   int* __restrict__ bcnt, int2* __restrict__ bents) {
    int e = blockIdx.x * 256 + threadIdx.x;
    if (e < NE) {
        int s = ei[e];
        int d = ei[NE + e];
        atomicAdd(&cnt[d], 1);
        int b = d >> 6;
        int off = atomicAdd(&bcnt[b], 1);
        bents[(size_t)b * BCAP + off] = make_int2(s, (e << 6) | (d & 63));
    }
}

__global__ void bsum_kernel(const int* __restrict__ cnt, int* __restrict__ bsum) {
    __shared__ int s[256];
    int t = threadIdx.x;
    int i = blockIdx.x * 256 + t;
    int v = (i < NN) ? cnt[i] : 0;
    s[t] = v;
    __syncthreads();
    for (int off = 128; off > 0; off >>= 1) {
        if (t < off) s[t] += s[t + off];
        __syncthreads();
    }
    if (t == 0) bsum[blockIdx.x] = s[0];
}

__global__ void bscan_kernel(const int* __restrict__ bsum, int* __restrict__ bpre, int nb) {
    __shared__ int s[256];
    int t = threadIdx.x;
    int v = (t < nb) ? bsum[t] : 0;
    s[t] = v;
    __syncthreads();
    for (int off = 1; off < 256; off <<= 1) {
        int w = (t >= off) ? s[t - off] : 0;
        __syncthreads();
        s[t] += w;
        __syncthreads();
    }
    if (t < nb) bpre[t] = s[t] - v;
}

__global__ void rowptr_kernel(const int* __restrict__ cnt, const int* __restrict__ bpre,
                              int* __restrict__ row_ptr) {
    __shared__ int s[256];
    int t = threadIdx.x;
    int i = blockIdx.x * 256 + t;
    int v = (i < NN) ? cnt[i] : 0;
    s[t] = v;
    __syncthreads();
    for (int off = 1; off < 256; off <<= 1) {
        int w = (t >= off) ? s[t - off] : 0;
        __syncthreads();
        s[t] += w;
        __syncthreads();
    }
    if (i < NN) row_ptr[i] = s[t] - v + bpre[blockIdx.x];
    if (i == 0) row_ptr[NN] = NE;
}

// pass B: one block per bucket; writes stay within the bucket's dst csr range.
__global__ void place_kernel(const int* __restrict__ bcnt, const int2* __restrict__ bents,
                             const int* __restrict__ row_ptr, int* __restrict__ cnt,
                             int2* __restrict__ csr) {
    int b = blockIdx.x;
    int n = bcnt[b];
    for (int i = threadIdx.x; i < n; i += 256) {
        int2 en = bents[(size_t)b * BCAP + i];
        int d = (b << 6) | (en.y & 63);
        int eid = en.y >> 6;
        int old = atomicSub(&cnt[d], 1);
        csr[row_ptr[d] + old - 1] = make_int2(en.x, eid);
    }
}

// segaug[v][32] (bf16) = [ segE[v][0..15], deg, 1, 0.. ]
__global__ __launch_bounds__(256) void sege_kernel(
    const int* __restrict__ row_ptr, const int2* __restrict__ csr,
    const float* __restrict__ ea, ushort_t* __restrict__ segaug) {
    int node = blockIdx.x * 4 + (threadIdx.x >> 6);
    if (node >= NN) return;
    int lane = threadIdx.x & 63;
    int G = lane >> 2, q4 = (lane & 3) * 4;
    int beg = row_ptr[node], end = row_ptr[node + 1];
    float4 a = make_float4(0.f, 0.f, 0.f, 0.f);
    for (int j = beg + G; j < end; j += 16) {
        int e = csr[j].y;
        float4 v = *(const float4*)(ea + (size_t)e * FE + q4);
        a.x += v.x; a.y += v.y; a.z += v.z; a.w += v.w;
    }
    for (int m = 4; m <= 32; m <<= 1) {
        a.x += __shfl_xor(a.x, m);
        a.y += __shfl_xor(a.y, m);
        a.z += __shfl_xor(a.z, m);
        a.w += __shfl_xor(a.w, m);
    }
    if (lane < 4) {
        ushort_t o[4] = {f2bf(a.x), f2bf(a.y), f2bf(a.z), f2bf(a.w)};
        *(uint2*)(segaug + (size_t)node * 32 + lane * 4) = *(uint2*)o;
    } else if (lane < 8) {
        ushort_t o[4] = {0, 0, 0, 0};
        if (lane == 4) { o[0] = f2bf((float)(end - beg)); o[1] = f2bf(1.f); }
        *(uint2*)(segaug + (size_t)node * 32 + lane * 4) = *(uint2*)o;
    }
}

// ---------------- weight repack into MFMA B-fragment order ----------------
// 0:W1_msg K64 @0 | 1:W1_self K64 @8192 | 2:eaug1 K32 @16384
// 3..5: Wk_msg K128 @20480+i*16384 | 6..8: eaug_i K32 @69632+i*4096
// eaug rows: 0..15=We, 16=bm+be, 17=const bias (b1_self or 0), rest 0.

__global__ void repack_kernel(const float* __restrict__ W1_msg,
                              const float* __restrict__ W1_self,
                              const float* __restrict__ W1_edge,
                              const float* __restrict__ b1_msg,
                              const float* __restrict__ b1_edge,
                              const float* __restrict__ b1_self,
                              const float* __restrict__ Wk_msg,
                              const float* __restrict__ Wk_edge,
                              const float* __restrict__ bk_msg,
                              const float* __restrict__ bk_edge,
                              ushort_t* __restrict__ pack) {
    int mid = blockIdx.y;
    const float *W = nullptr, *bm = nullptr, *be = nullptr, *bc = nullptr;
    int K;
    size_t doff;
    bool aug = false;
    if (mid == 0)      { W = W1_msg;  K = 64;  doff = 0; }
    else if (mid == 1) { W = W1_self; K = 64;  doff = 8192; }
    else if (mid == 2) { W = W1_edge; bm = b1_msg; be = b1_edge; bc = b1_self;
                         K = 32; doff = 16384; aug = true; }
    else if (mid <= 5) { int i = mid - 3; W = Wk_msg + (size_t)i * HD * HD;
                         K = 128; doff = 20480 + (size_t)i * 16384; }
    else               { int i = mid - 6; W = Wk_edge + (size_t)i * FE * HD;
                         bm = bk_msg + i * HD; be = bk_edge + i * HD;
                         K = 32; doff = 69632 + (size_t)i * 4096; aug = true; }
    int KS = K / 32;
    int t = blockIdx.x * 256 + threadIdx.x;
    if (t >= 8 * KS * 64) return;
    int lane = t & 63;
    int nk = t >> 6;
    int ks = nk % KS, nt = nk / KS;
    int n = nt * 16 + (lane & 15);
    int kb = ks * 32 + (lane >> 4) * 8;
    ushort_t o[8];
#pragma unroll
    for (int j = 0; j < 8; ++j) {
        int k = kb + j;
        float v;
        if (!aug)         v = W[(size_t)k * HD + n];
        else if (k < 16)  v = W[(size_t)k * HD + n];
        else if (k == 16) v = bm[n] + be[n];
        else if (k == 17) v = bc ? bc[n] : 0.f;
        else              v = 0.f;
        o[j] = f2bf(v);
    }
    *(uint4*)(pack + doff + (size_t)t * 8) = *(uint4*)o;
}

// ---------------- conv1 GEMM: Cm = x@W1_msg ; Cs = x@W1_self + segaug@eaug1 ----------------

__global__ __launch_bounds__(256) void gemm_mfma_conv1(const float* __restrict__ A,
                                                       const ushort_t* __restrict__ segaug,
                                                       const ushort_t* __restrict__ pack,
                                                       ushort_t* __restrict__ Cm,
                                                       ushort_t* __restrict__ Cs, int n) {
    constexpr int STR = 72, SSTR = 40;
    __shared__ __align__(16) ushort_t As[64 * STR];
    __shared__ __align__(16) ushort_t Ss[64 * SSTR];
    int tid = threadIdx.x;
    int row0 = blockIdx.x * 64;
#pragma unroll
    for (int p = 0; p < 2; ++p) {
        int c = p * 256 + tid;
        int r = c >> 3, col = (c & 7) * 8;
        int gr = row0 + r;
        float4 f0 = make_float4(0.f, 0.f, 0.f, 0.f), f1 = f0;
        if (gr < n) {
            f0 = *(const float4*)(A + (size_t)gr * FN + col);
            f1 = *(const float4*)(A + (size_t)gr * FN + col + 4);
        }
        ushort_t o[8] = {f2bf(f0.x), f2bf(f0.y), f2bf(f0.z), f2bf(f0.w),
                         f2bf(f1.x), f2bf(f1.y), f2bf(f1.z), f2bf(f1.w)};
        *(uint4*)(&As[r * STR + col]) = *(uint4*)o;
    }
    {
        int c = tid;
        int r = c >> 2, col = (c & 3) * 8;
        int gr = row0 + r;
        uint4 v = make_uint4(0u, 0u, 0u, 0u);
        if (gr < n) v = *(const uint4*)(segaug + (size_t)gr * 32 + col);
        *(uint4*)(&Ss[r * SSTR + col]) = v;
    }
    __syncthreads();
    int lane = tid & 63, wave = tid >> 6;
    int m = lane & 15, quad = lane >> 4;
    f32x4 acc[16];
#pragma unroll
    for (int i = 0; i < 16; ++i) acc[i] = (f32x4)(0.f);
    const short8* Bmsg = (const short8*)pack;
    const short8* Bself = (const short8*)(pack + 8192);
    const short8* Beaug = (const short8*)(pack + 16384);
#pragma unroll
    for (int ks = 0; ks < 2; ++ks) {
        short8 a = *(const short8*)(&As[(wave * 16 + m) * STR + ks * 32 + quad * 8]);
#pragma unroll
        for (int nt = 0; nt < 8; ++nt) {
            acc[nt] = __builtin_amdgcn_mfma_f32_16x16x32_bf16(
                a, Bmsg[(nt * 2 + ks) * 64 + lane], acc[nt], 0, 0, 0);
            acc[8 + nt] = __builtin_amdgcn_mfma_f32_16x16x32_bf16(
                a, Bself[(nt * 2 + ks) * 64 + lane], acc[8 + nt], 0, 0, 0);
        }
    }
    {
        short8 sa = *(const short8*)(&Ss[(wave * 16 + m) * SSTR + quad * 8]);
#pragma unroll
        for (int nt = 0; nt < 8; ++nt)
            acc[8 + nt] = __builtin_amdgcn_mfma_f32_16x16x32_bf16(
                sa, Beaug[nt * 64 + lane], acc[8 + nt], 0, 0, 0);
    }
#pragma unroll
    for (int nt = 0; nt < 8; ++nt) {
        int col = nt * 16 + m;
#pragma unroll
        for (int r = 0; r < 4; ++r) {
            int grow = row0 + wave * 16 + quad * 4 + r;
            if (grow < n) {
                Cm[(size_t)grow * HD + col] = f2bf(acc[nt][r]);
                Cs[(size_t)grow * HD + col] = f2bf(acc[8 + nt][r]);
            }
        }
    }
}

// ---------------- fused layer kernel: agg_i + gemm_{i+1} ----------------

__device__ __forceinline__ void accum8(float* a, uint4 v) {
    a[0] += __uint_as_float(v.x << 16);
    a[1] += __uint_as_float(v.x & 0xffff0000u);
    a[2] += __uint_as_float(v.y << 16);
    a[3] += __uint_as_float(v.y & 0xffff0000u);
    a[4] += __uint_as_float(v.z << 16);
    a[5] += __uint_as_float(v.z & 0xffff0000u);
    a[6] += __uint_as_float(v.w << 16);
    a[7] += __uint_as_float(v.w & 0xffff0000u);
}

__global__ __launch_bounds__(256, 6) void fused_agg_gemm(
    const int* __restrict__ row_ptr, const int2* __restrict__ csr,
    const ushort_t* __restrict__ msg_in, const ushort_t* __restrict__ S_in,
    const ushort_t* __restrict__ segaug, const ushort_t* __restrict__ Bm,
    const ushort_t* __restrict__ Be, ushort_t* __restrict__ msg_out,
    ushort_t* __restrict__ S_out) {
    constexpr int STR = 136, SSTR = 40;
    __shared__ __align__(16) ushort_t Hs[16 * STR];
    __shared__ __align__(16) ushort_t Ss[16 * SSTR];
    int tid = threadIdx.x;
    int node0 = blockIdx.x * 16;
    if (tid < 64) {
        int r = tid >> 2, col = (tid & 3) * 8;
        *(uint4*)(&Ss[r * SSTR + col]) =
            *(const uint4*)(segaug + (size_t)(node0 + r) * 32 + col);
    }
    int nl = tid >> 4;
    int node = node0 + nl;
    int c8 = (tid & 15) * 8;
    int beg = row_ptr[node], end = row_ptr[node + 1];
    float a0[8] = {0.f, 0.f, 0.f, 0.f, 0.f, 0.f, 0.f, 0.f};
    float a1[8] = {0.f, 0.f, 0.f, 0.f, 0.f, 0.f, 0.f, 0.f};
    int j = beg;
    for (; j + 3 < end; j += 4) {
        int u0 = csr[j].x, u1 = csr[j + 1].x, u2 = csr[j + 2].x, u3 = csr[j + 3].x;
        uint4 v0 = *(const uint4*)(msg_in + (size_t)u0 * HD + c8);
        uint4 v1 = *(const uint4*)(msg_in + (size_t)u1 * HD + c8);
        uint4 v2 = *(const uint4*)(msg_in + (size_t)u2 * HD + c8);
        uint4 v3 = *(const uint4*)(msg_in + (size_t)u3 * HD + c8);
        accum8(a0, v0);
        accum8(a1, v1);
        accum8(a0, v2);
        accum8(a1, v3);
    }
    for (; j < end; ++j) {
        uint4 v = *(const uint4*)(msg_in + (size_t)csr[j].x * HD + c8);
        accum8(a0, v);
    }
    accum8(a0, *(const uint4*)(S_in + (size_t)node * HD + c8));
    {
        ushort_t h8[8];
#pragma unroll
        for (int i = 0; i < 8; ++i) h8[i] = f2bf(fmaxf(a0[i] + a1[i], 0.f));
        *(uint4*)(&Hs[nl * STR + c8]) = *(uint4*)h8;
    }
    __syncthreads();
    int lane = tid & 63, wave = tid >> 6;
    int m = lane & 15, quad = lane >> 4;
    f32x4 acc[2], accE[2];
#pragma unroll
    for (int t = 0; t < 2; ++t) { acc[t] = (f32x4)(0.f); accE[t] = (f32x4)(0.f); }
    const short8* Bmv = (const short8*)Bm;
    const short8* Bev = (const short8*)Be;
#pragma unroll
    for (int ks = 0; ks < 4; ++ks) {
        short8 a = *(const short8*)(&Hs[m * STR + ks * 32 + quad * 8]);
#pragma unroll
        for (int t = 0; t < 2; ++t) {
            int nt = wave * 2 + t;
            acc[t] = __builtin_amdgcn_mfma_f32_16x16x32_bf16(
                a, Bmv[(nt * 4 + ks) * 64 + lane], acc[t], 0, 0, 0);
        }
    }
    {
        short8 sa = *(const short8*)(&Ss[m * SSTR + quad * 8]);
#pragma unroll
        for (int t = 0; t < 2; ++t) {
            int nt = wave * 2 + t;
            accE[t] = __builtin_amdgcn_mfma_f32_16x16x32_bf16(
                sa, Bev[nt * 64 + lane], accE[t], 0, 0, 0);
        }
    }
#pragma unroll
    for (int t = 0; t < 2; ++t) {
        int col = (wave * 2 + t) * 16 + m;
#pragma unroll
        for (int r = 0; r < 4; ++r) {
            int rl = quad * 4 + r;
            size_t gidx = (size_t)(node0 + rl) * HD + col;
            msg_out[gidx] = f2bf(acc[t][r]);
            S_out[gidx] = f2bf(accE[t][r] + bf2f(Hs[rl * STR + col]));
        }
    }
}

// ---------------- final aggregate: h4 = relu(sum_nbr msg + S) ----------------

__global__ __launch_bounds__(256, 6) void agg_kernel(
    const int* __restrict__ row_ptr, const int2* __restrict__ csr,
    const ushort_t* __restrict__ xm, const ushort_t* __restrict__ selfb,
    ushort_t* __restrict__ out, int n) {
    int tid = threadIdx.x;
    int node = blockIdx.x * 16 + (tid >> 4);
    if (node >= n) return;
    int c8 = (tid & 15) * 8;
    int beg = row_ptr[node], end = row_ptr[node + 1];
    float a0[8] = {0.f, 0.f, 0.f, 0.f, 0.f, 0.f, 0.f, 0.f};
    float a1[8] = {0.f, 0.f, 0.f, 0.f, 0.f, 0.f, 0.f, 0.f};
    int j = beg;
    for (; j + 3 < end; j += 4) {
        int u0 = csr[j].x, u1 = csr[j + 1].x, u2 = csr[j + 2].x, u3 = csr[j + 3].x;
        uint4 v0 = *(const uint4*)(xm + (size_t)u0 * HD + c8);
        uint4 v1 = *(const uint4*)(xm + (size_t)u1 * HD + c8);
        uint4 v2 = *(const uint4*)(xm + (size_t)u2 * HD + c8);
        uint4 v3 = *(const uint4*)(xm + (size_t)u3 * HD + c8);
        accum8(a0, v0);
        accum8(a1, v1);
        accum8(a0, v2);
        accum8(a1, v3);
    }
    for (; j < end; ++j) {
        uint4 v = *(const uint4*)(xm + (size_t)csr[j].x * HD + c8);
        accum8(a0, v);
    }
    accum8(a0, *(const uint4*)(selfb + (size_t)node * HD + c8));
    ushort_t o[8];
#pragma unroll
    for (int i = 0; i < 8; ++i) o[i] = f2bf(fmaxf(a0[i] + a1[i], 0.f));
    *(uint4*)(out + (size_t)node * HD + c8) = *(uint4*)o;
}

// ---------------- mean pool (batch sorted): 4 partial blocks per graph ----------------

__global__ void pool_partial(const ushort_t* __restrict__ h, const int* __restrict__ batch,
                             float* __restrict__ pooled4) {
    int g = blockIdx.x;
    int q = blockIdx.y;
    int f = threadIdx.x;
    int lo = 0, hi = NN;
    while (lo < hi) { int m = (lo + hi) >> 1; if (batch[m] < g) lo = m + 1; else hi = m; }
    int s = lo;
    lo = s; hi = NN;
    while (lo < hi) { int m = (lo + hi) >> 1; if (batch[m] < g + 1) lo = m + 1; else hi = m; }
    int e = lo;
    int len = e - s;
    int c0 = s + (len * q) / 4;
    int c1 = s + (len * (q + 1)) / 4;
    float acc = 0.f;
    for (int v = c0; v < c1; ++v) acc += bf2f(h[(size_t)v * HD + f]);
    pooled4[((size_t)q * NG + g) * HD + f] = acc;
}

// ---------------- fusion head ----------------

__global__ void head_kernel(const float* __restrict__ pooled4, const int* __restrict__ batch,
                            const float* __restrict__ lf, const float* __restrict__ pfe,
                            const float* __restrict__ Wl, const float* __restrict__ bl,
                            const float* __restrict__ Wp, const float* __restrict__ bp,
                            const float* __restrict__ Wf, const float* __restrict__ bfv,
                            const float* __restrict__ Wo, const float* __restrict__ bo,
                            float* __restrict__ out) {
    __shared__ float cat[3 * HD];
    __shared__ float red[HD];
    int g = blockIdx.x, j = threadIdx.x;
    int lo = 0, hi = NN;
    while (lo < hi) { int m = (lo + hi) >> 1; if (batch[m] < g) lo = m + 1; else hi = m; }
    int s0 = lo;
    lo = s0; hi = NN;
    while (lo < hi) { int m = (lo + hi) >> 1; if (batch[m] < g + 1) lo = m + 1; else hi = m; }
    float cntf = (float)(lo - s0);
    float p = pooled4[(size_t)g * HD + j] + pooled4[((size_t)NG + g) * HD + j] +
              pooled4[((size_t)2 * NG + g) * HD + j] + pooled4[((size_t)3 * NG + g) * HD + j];
    cat[j] = p / fmaxf(cntf, 1.f);
    float s = bl[j];
    for (int k = 0; k < FL; ++k) s += lf[g * FL + k] * Wl[k * HD + j];
    cat[HD + j] = s;
    s = bp[j];
    for (int k = 0; k < FPOC; ++k) s += pfe[g * FPOC + k] * Wp[k * HD + j];
    cat[2 * HD + j] = s;
    __syncthreads();
    float fj = bfv[j];
    for (int k = 0; k < 3 * HD; ++k) fj += cat[k] * Wf[k * HD + j];
    red[j] = fj * Wo[j];
    __syncthreads();
    for (int off = 64; off > 0; off >>= 1) {
        if (j < off) red[j] += red[j + off];
        __syncthreads();
    }
    if (j == 0) out[g] = red[0] + bo[0];
}

// ---------------- launch ----------------

extern "C" void kernel_launch(void* const* d_in, const int* in_sizes, int n_in,
                              void* d_out, int out_size, void* d_ws, size_t ws_size,
                              hipStream_t stream) {
    const float* x       = (const float*)d_in[0];
    const int*   ei      = (const int*)d_in[1];
    const float* ea      = (const float*)d_in[2];
    const int*   batch   = (const int*)d_in[3];
    const float* lf      = (const float*)d_in[4];
    const float* pfe     = (const float*)d_in[5];
    const float* W1_msg  = (const float*)d_in[6];
    const float* b1_msg  = (const float*)d_in[7];
    const float* W1_edge = (const float*)d_in[8];
    const float* b1_edge = (const float*)d_in[9];
    const float* W1_self = (const float*)d_in[10];
    const float* b1_self = (const float*)d_in[11];
    const float* Wk_msg  = (const float*)d_in[12];
    const float* bk_msg  = (const float*)d_in[13];
    const float* Wk_edge = (const float*)d_in[14];
    const float* bk_edge = (const float*)d_in[15];
    const float* Wl      = (const float*)d_in[16];
    const float* bl      = (const float*)d_in[17];
    const float* Wp      = (const float*)d_in[18];
    const float* bp      = (const float*)d_in[19];
    const float* Wf      = (const float*)d_in[20];
    const float* bfv     = (const float*)d_in[21];
    const float* Wo      = (const float*)d_in[22];
    const float* bo      = (const float*)d_in[23];

    char* wsp = (char*)d_ws;
    size_t off = 0;
    auto carve = [&](size_t bytes) -> void* {
        char* p = wsp + off;
        off += (bytes + 255) & ~(size_t)255;
        return (void*)p;
    };
    int*      cnt     = (int*)carve((size_t)(NN + NBUCK) * 4);  // cnt + bcnt, one memset
    int*      bcnt    = cnt + NN;
    int*      row_ptr = (int*)carve((size_t)(NN + 1) * 4);
    int2*     csr     = (int2*)carve((size_t)NE * 8);
    ushort_t* segaug  = (ushort_t*)carve((size_t)NN * 32 * 2);
    ushort_t* pack    = (ushort_t*)carve((size_t)81920 * 2);
    ushort_t* bufC    = (ushort_t*)carve((size_t)NN * HD * 2);  // msg ping
    ushort_t* bufD    = (ushort_t*)carve((size_t)NN * HD * 2);  // msg pong
    ushort_t* bufS    = (ushort_t*)carve((size_t)NN * HD * 2);  // S ping
    ushort_t* bufT    = (ushort_t*)carve((size_t)NN * HD * 2);  // S pong
    float*    pooled4 = (float*)carve((size_t)4 * NG * HD * 4);
    int*      bsum    = (int*)carve((size_t)256 * 4);
    int*      bpre    = (int*)carve((size_t)256 * 4);
    // bucket staging aliases bufC (dead until conv1; stream-ordered => safe)
    int2*     bents   = (int2*)bufC;   // NBUCK*BCAP*8 = 9.6MB <= 12.8MB

    const int NBLK = (NN + 255) / 256;

    hipMemsetAsync(cnt, 0, (size_t)(NN + NBUCK) * 4, stream);

    countbucket_kernel<<<(NE + 255) / 256, 256, 0, stream>>>(ei, cnt, bcnt, bents);
    bsum_kernel<<<NBLK, 256, 0, stream>>>(cnt, bsum);
    bscan_kernel<<<1, 256, 0, stream>>>(bsum, bpre, NBLK);
    rowptr_kernel<<<NBLK, 256, 0, stream>>>(cnt, bpre, row_ptr);
    place_kernel<<<NBUCK, 256, 0, stream>>>(bcnt, bents, row_ptr, cnt, csr);
    sege_kernel<<<(NN + 3) / 4, 256, 0, stream>>>(row_ptr, csr, ea, segaug);
    repack_kernel<<<dim3(8, 9), 256, 0, stream>>>(W1_msg, W1_self, W1_edge, b1_msg,
                                                  b1_edge, b1_self, Wk_msg, Wk_edge,
                                                  bk_msg, bk_edge, pack);

    // conv1: msg1 -> bufC, S1 = x@W1_self + edge-term -> bufS
    gemm_mfma_conv1<<<dim3((NN + 63) / 64), 256, 0, stream>>>(x, segaug, pack, bufC,
                                                              bufS, NN);
    // fused layers (h stays on-chip)
    fused_agg_gemm<<<NN / 16, 256, 0, stream>>>(row_ptr, csr, bufC, bufS, segaug,
                                                pack + 20480, pack + 69632, bufD, bufT);
    fused_agg_gemm<<<NN / 16, 256, 0, stream>>>(row_ptr, csr, bufD, bufT, segaug,
                                                pack + 20480 + 16384, pack + 69632 + 4096,
                                                bufC, bufS);
    fused_agg_gemm<<<NN / 16, 256, 0, stream>>>(row_ptr, csr, bufC, bufS, segaug,
                                                pack + 20480 + 32768, pack + 69632 + 8192,
                                                bufD, bufT);
    agg_kernel<<<(NN + 15) / 16, 256, 0, stream>>>(row_ptr, csr, bufD, bufT, bufC, NN);

    pool_partial<<<dim3(NG, 4), HD, 0, stream>>>(bufC, batch, pooled4);
    head_kernel<<<NG, HD, 0, stream>>>(pooled4, batch, lf, pfe, Wl, bl, Wp, bp, Wf, bfv,
                                       Wo, bo, (float*)d_out);
}

// Round 11
// 377.424 us; speedup vs baseline: 1.4744x; 1.4744x over previous
//
#include <hip/hip_runtime.h>
#include <cstdint>

#define NN 50000
#define NE 640000
#define NG 128
#define HD 128
#define FN 64
#define FE 16
#define FL 200
#define FPOC 100
#define NSTACK 3

typedef unsigned short ushort_t;
typedef short short8 __attribute__((ext_vector_type(8)));
typedef float f32x4 __attribute__((ext_vector_type(4)));

__device__ __forceinline__ ushort_t f2bf(float f) {
    unsigned u = __float_as_uint(f);
    unsigned r = (u + 0x7fffu + ((u >> 16) & 1u)) >> 16;
    return (ushort_t)r;
}
__device__ __forceinline__ float bf2f(ushort_t u) {
    return __uint_as_float(((unsigned)u) << 16);
}

// ---------------- CSR build (round-8 proven scheme) ----------------
// NOTE (round 9 post-mortem): bucketed two-pass scatter regressed 4x —
// 640k return-atomics over 782 counters serialize, and cross-XCD interleaved
// writes to shared bucket-tail lines re-amplify (51MB). Keep the direct int2
// scatter: 43MB amplification but only ~45us.

__global__ void count_kernel(const int* __restrict__ ei, int* __restrict__ cnt) {
    int e = blockIdx.x * 256 + threadIdx.x;
    if (e < NE) atomicAdd(&cnt[ei[NE + e]], 1);
}

__global__ void bsum_kernel(const int* __restrict__ cnt, int* __restrict__ bsum) {
    __shared__ int s[256];
    int t = threadIdx.x;
    int i = blockIdx.x * 256 + t;
    int v = (i < NN) ? cnt[i] : 0;
    s[t] = v;
    __syncthreads();
    for (int off = 128; off > 0; off >>= 1) {
        if (t < off) s[t] += s[t + off];
        __syncthreads();
    }
    if (t == 0) bsum[blockIdx.x] = s[0];
}

__global__ void bscan_kernel(const int* __restrict__ bsum, int* __restrict__ bpre, int nb) {
    __shared__ int s[256];
    int t = threadIdx.x;
    int v = (t < nb) ? bsum[t] : 0;
    s[t] = v;
    __syncthreads();
    for (int off = 1; off < 256; off <<= 1) {
        int w = (t >= off) ? s[t - off] : 0;
        __syncthreads();
        s[t] += w;
        __syncthreads();
    }
    if (t < nb) bpre[t] = s[t] - v;
}

__global__ void rowptr_kernel(const int* __restrict__ cnt, const int* __restrict__ bpre,
                              int* __restrict__ row_ptr) {
    __shared__ int s[256];
    int t = threadIdx.x;
    int i = blockIdx.x * 256 + t;
    int v = (i < NN) ? cnt[i] : 0;
    s[t] = v;
    __syncthreads();
    for (int off = 1; off < 256; off <<= 1) {
        int w = (t >= off) ? s[t - off] : 0;
        __syncthreads();
        s[t] += w;
        __syncthreads();
    }
    if (i < NN) row_ptr[i] = s[t] - v + bpre[blockIdx.x];
    if (i == 0) row_ptr[NN] = NE;
}

__global__ void fill_kernel(const int* __restrict__ ei, const int* __restrict__ row_ptr,
                            int* __restrict__ cnt, int2* __restrict__ csr) {
    int e = blockIdx.x * 256 + threadIdx.x;
    if (e < NE) {
        int s = ei[e];
        int d = ei[NE + e];
        int old = atomicSub(&cnt[d], 1);
        csr[row_ptr[d] + old - 1] = make_int2(s, e);
    }
}

// segaug[v][32] (bf16) = [ segE[v][0..15], deg, 1, 0.. ]
__global__ __launch_bounds__(256) void sege_kernel(
    const int* __restrict__ row_ptr, const int2* __restrict__ csr,
    const float* __restrict__ ea, ushort_t* __restrict__ segaug) {
    int node = blockIdx.x * 4 + (threadIdx.x >> 6);
    if (node >= NN) return;
    int lane = threadIdx.x & 63;
    int G = lane >> 2, q4 = (lane & 3) * 4;
    int beg = row_ptr[node], end = row_ptr[node + 1];
    float4 a = make_float4(0.f, 0.f, 0.f, 0.f);
    for (int j = beg + G; j < end; j += 16) {
        int e = csr[j].y;
        float4 v = *(const float4*)(ea + (size_t)e * FE + q4);
        a.x += v.x; a.y += v.y; a.z += v.z; a.w += v.w;
    }
    for (int m = 4; m <= 32; m <<= 1) {
        a.x += __shfl_xor(a.x, m);
        a.y += __shfl_xor(a.y, m);
        a.z += __shfl_xor(a.z, m);
        a.w += __shfl_xor(a.w, m);
    }
    if (lane < 4) {
        ushort_t o[4] = {f2bf(a.x), f2bf(a.y), f2bf(a.z), f2bf(a.w)};
        *(uint2*)(segaug + (size_t)node * 32 + lane * 4) = *(uint2*)o;
    } else if (lane < 8) {
        ushort_t o[4] = {0, 0, 0, 0};
        if (lane == 4) { o[0] = f2bf((float)(end - beg)); o[1] = f2bf(1.f); }
        *(uint2*)(segaug + (size_t)node * 32 + lane * 4) = *(uint2*)o;
    }
}

// ---------------- weight repack into MFMA B-fragment order ----------------
// 0:W1_msg K64 @0 | 1:W1_self K64 @8192 | 2:eaug1 K32 @16384
// 3..5: Wk_msg K128 @20480+i*16384 | 6..8: eaug_i K32 @69632+i*4096

__global__ void repack_kernel(const float* __restrict__ W1_msg,
                              const float* __restrict__ W1_self,
                              const float* __restrict__ W1_edge,
                              const float* __restrict__ b1_msg,
                              const float* __restrict__ b1_edge,
                              const float* __restrict__ b1_self,
                              const float* __restrict__ Wk_msg,
                              const float* __restrict__ Wk_edge,
                              const float* __restrict__ bk_msg,
                              const float* __restrict__ bk_edge,
                              ushort_t* __restrict__ pack) {
    int mid = blockIdx.y;
    const float *W = nullptr, *bm = nullptr, *be = nullptr, *bc = nullptr;
    int K;
    size_t doff;
    bool aug = false;
    if (mid == 0)      { W = W1_msg;  K = 64;  doff = 0; }
    else if (mid == 1) { W = W1_self; K = 64;  doff = 8192; }
    else if (mid == 2) { W = W1_edge; bm = b1_msg; be = b1_edge; bc = b1_self;
                         K = 32; doff = 16384; aug = true; }
    else if (mid <= 5) { int i = mid - 3; W = Wk_msg + (size_t)i * HD * HD;
                         K = 128; doff = 20480 + (size_t)i * 16384; }
    else               { int i = mid - 6; W = Wk_edge + (size_t)i * FE * HD;
                         bm = bk_msg + i * HD; be = bk_edge + i * HD;
                         K = 32; doff = 69632 + (size_t)i * 4096; aug = true; }
    int KS = K / 32;
    int t = blockIdx.x * 256 + threadIdx.x;
    if (t >= 8 * KS * 64) return;
    int lane = t & 63;
    int nk = t >> 6;
    int ks = nk % KS, nt = nk / KS;
    int n = nt * 16 + (lane & 15);
    int kb = ks * 32 + (lane >> 4) * 8;
    ushort_t o[8];
#pragma unroll
    for (int j = 0; j < 8; ++j) {
        int k = kb + j;
        float v;
        if (!aug)         v = W[(size_t)k * HD + n];
        else if (k < 16)  v = W[(size_t)k * HD + n];
        else if (k == 16) v = bm[n] + be[n];
        else if (k == 17) v = bc ? bc[n] : 0.f;
        else              v = 0.f;
        o[j] = f2bf(v);
    }
    *(uint4*)(pack + doff + (size_t)t * 8) = *(uint4*)o;
}

// ---------------- conv1 GEMM: Cm = x@W1_msg ; Cs = x@W1_self + segaug@eaug1 ----------------

__global__ __launch_bounds__(256) void gemm_mfma_conv1(const float* __restrict__ A,
                                                       const ushort_t* __restrict__ segaug,
                                                       const ushort_t* __restrict__ pack,
                                                       ushort_t* __restrict__ Cm,
                                                       ushort_t* __restrict__ Cs, int n) {
    constexpr int STR = 72, SSTR = 40;
    __shared__ __align__(16) ushort_t As[64 * STR];
    __shared__ __align__(16) ushort_t Ss[64 * SSTR];
    int tid = threadIdx.x;
    int row0 = blockIdx.x * 64;
#pragma unroll
    for (int p = 0; p < 2; ++p) {
        int c = p * 256 + tid;
        int r = c >> 3, col = (c & 7) * 8;
        int gr = row0 + r;
        float4 f0 = make_float4(0.f, 0.f, 0.f, 0.f), f1 = f0;
        if (gr < n) {
            f0 = *(const float4*)(A + (size_t)gr * FN + col);
            f1 = *(const float4*)(A + (size_t)gr * FN + col + 4);
        }
        ushort_t o[8] = {f2bf(f0.x), f2bf(f0.y), f2bf(f0.z), f2bf(f0.w),
                         f2bf(f1.x), f2bf(f1.y), f2bf(f1.z), f2bf(f1.w)};
        *(uint4*)(&As[r * STR + col]) = *(uint4*)o;
    }
    {
        int c = tid;
        int r = c >> 2, col = (c & 3) * 8;
        int gr = row0 + r;
        uint4 v = make_uint4(0u, 0u, 0u, 0u);
        if (gr < n) v = *(const uint4*)(segaug + (size_t)gr * 32 + col);
        *(uint4*)(&Ss[r * SSTR + col]) = v;
    }
    __syncthreads();
    int lane = tid & 63, wave = tid >> 6;
    int m = lane & 15, quad = lane >> 4;
    f32x4 acc[16];
#pragma unroll
    for (int i = 0; i < 16; ++i) acc[i] = (f32x4)(0.f);
    const short8* Bmsg = (const short8*)pack;
    const short8* Bself = (const short8*)(pack + 8192);
    const short8* Beaug = (const short8*)(pack + 16384);
#pragma unroll
    for (int ks = 0; ks < 2; ++ks) {
        short8 a = *(const short8*)(&As[(wave * 16 + m) * STR + ks * 32 + quad * 8]);
#pragma unroll
        for (int nt = 0; nt < 8; ++nt) {
            acc[nt] = __builtin_amdgcn_mfma_f32_16x16x32_bf16(
                a, Bmsg[(nt * 2 + ks) * 64 + lane], acc[nt], 0, 0, 0);
            acc[8 + nt] = __builtin_amdgcn_mfma_f32_16x16x32_bf16(
                a, Bself[(nt * 2 + ks) * 64 + lane], acc[8 + nt], 0, 0, 0);
        }
    }
    {
        short8 sa = *(const short8*)(&Ss[(wave * 16 + m) * SSTR + quad * 8]);
#pragma unroll
        for (int nt = 0; nt < 8; ++nt)
            acc[8 + nt] = __builtin_amdgcn_mfma_f32_16x16x32_bf16(
                sa, Beaug[nt * 64 + lane], acc[8 + nt], 0, 0, 0);
    }
#pragma unroll
    for (int nt = 0; nt < 8; ++nt) {
        int col = nt * 16 + m;
#pragma unroll
        for (int r = 0; r < 4; ++r) {
            int grow = row0 + wave * 16 + quad * 4 + r;
            if (grow < n) {
                Cm[(size_t)grow * HD + col] = f2bf(acc[nt][r]);
                Cs[(size_t)grow * HD + col] = f2bf(acc[8 + nt][r]);
            }
        }
    }
}

// ---------------- fused layer kernel: agg_i + gemm_{i+1} ----------------

__device__ __forceinline__ void accum8(float* a, uint4 v) {
    a[0] += __uint_as_float(v.x << 16);
    a[1] += __uint_as_float(v.x & 0xffff0000u);
    a[2] += __uint_as_float(v.y << 16);
    a[3] += __uint_as_float(v.y & 0xffff0000u);
    a[4] += __uint_as_float(v.z << 16);
    a[5] += __uint_as_float(v.z & 0xffff0000u);
    a[6] += __uint_as_float(v.w << 16);
    a[7] += __uint_as_float(v.w & 0xffff0000u);
}

__global__ __launch_bounds__(256, 6) void fused_agg_gemm(
    const int* __restrict__ row_ptr, const int2* __restrict__ csr,
    const ushort_t* __restrict__ msg_in, const ushort_t* __restrict__ S_in,
    const ushort_t* __restrict__ segaug, const ushort_t* __restrict__ Bm,
    const ushort_t* __restrict__ Be, ushort_t* __restrict__ msg_out,
    ushort_t* __restrict__ S_out) {
    constexpr int STR = 136, SSTR = 40;
    __shared__ __align__(16) ushort_t Hs[16 * STR];
    __shared__ __align__(16) ushort_t Ss[16 * SSTR];
    int tid = threadIdx.x;
    int node0 = blockIdx.x * 16;
    if (tid < 64) {
        int r = tid >> 2, col = (tid & 3) * 8;
        *(uint4*)(&Ss[r * SSTR + col]) =
            *(const uint4*)(segaug + (size_t)(node0 + r) * 32 + col);
    }
    int nl = tid >> 4;
    int node = node0 + nl;
    int c8 = (tid & 15) * 8;
    int beg = row_ptr[node], end = row_ptr[node + 1];
    float a0[8] = {0.f, 0.f, 0.f, 0.f, 0.f, 0.f, 0.f, 0.f};
    float a1[8] = {0.f, 0.f, 0.f, 0.f, 0.f, 0.f, 0.f, 0.f};
    int j = beg;
    for (; j + 3 < end; j += 4) {
        int u0 = csr[j].x, u1 = csr[j + 1].x, u2 = csr[j + 2].x, u3 = csr[j + 3].x;
        uint4 v0 = *(const uint4*)(msg_in + (size_t)u0 * HD + c8);
        uint4 v1 = *(const uint4*)(msg_in + (size_t)u1 * HD + c8);
        uint4 v2 = *(const uint4*)(msg_in + (size_t)u2 * HD + c8);
        uint4 v3 = *(const uint4*)(msg_in + (size_t)u3 * HD + c8);
        accum8(a0, v0);
        accum8(a1, v1);
        accum8(a0, v2);
        accum8(a1, v3);
    }
    for (; j < end; ++j) {
        uint4 v = *(const uint4*)(msg_in + (size_t)csr[j].x * HD + c8);
        accum8(a0, v);
    }
    accum8(a0, *(const uint4*)(S_in + (size_t)node * HD + c8));
    {
        ushort_t h8[8];
#pragma unroll
        for (int i = 0; i < 8; ++i) h8[i] = f2bf(fmaxf(a0[i] + a1[i], 0.f));
        *(uint4*)(&Hs[nl * STR + c8]) = *(uint4*)h8;
    }
    __syncthreads();
    int lane = tid & 63, wave = tid >> 6;
    int m = lane & 15, quad = lane >> 4;
    f32x4 acc[2], accE[2];
#pragma unroll
    for (int t = 0; t < 2; ++t) { acc[t] = (f32x4)(0.f); accE[t] = (f32x4)(0.f); }
    const short8* Bmv = (const short8*)Bm;
    const short8* Bev = (const short8*)Be;
#pragma unroll
    for (int ks = 0; ks < 4; ++ks) {
        short8 a = *(const short8*)(&Hs[m * STR + ks * 32 + quad * 8]);
#pragma unroll
        for (int t = 0; t < 2; ++t) {
            int nt = wave * 2 + t;
            acc[t] = __builtin_amdgcn_mfma_f32_16x16x32_bf16(
                a, Bmv[(nt * 4 + ks) * 64 + lane], acc[t], 0, 0, 0);
        }
    }
    {
        short8 sa = *(const short8*)(&Ss[m * SSTR + quad * 8]);
#pragma unroll
        for (int t = 0; t < 2; ++t) {
            int nt = wave * 2 + t;
            accE[t] = __builtin_amdgcn_mfma_f32_16x16x32_bf16(
                sa, Bev[nt * 64 + lane], accE[t], 0, 0, 0);
        }
    }
#pragma unroll
    for (int t = 0; t < 2; ++t) {
        int col = (wave * 2 + t) * 16 + m;
#pragma unroll
        for (int r = 0; r < 4; ++r) {
            int rl = quad * 4 + r;
            size_t gidx = (size_t)(node0 + rl) * HD + col;
            msg_out[gidx] = f2bf(acc[t][r]);
            S_out[gidx] = f2bf(accE[t][r] + bf2f(Hs[rl * STR + col]));
        }
    }
}

// ---------------- final aggregate fused with pooling ----------------
// h4 = relu(gather + S) is consumed ONLY by mean-pool -> never write it to
// global. Stage the block's 16 fp32 rows in LDS; threads 0..127 run-length
// sum along sorted batch ids and atomicAdd per graph-segment (~128-256
// atomics/block into 64KB pooled).

__global__ __launch_bounds__(256, 6) void agg_pool_kernel(
    const int* __restrict__ row_ptr, const int2* __restrict__ csr,
    const ushort_t* __restrict__ xm, const ushort_t* __restrict__ selfb,
    const int* __restrict__ batch, float* __restrict__ pooled) {
    __shared__ float hloc[16][HD];
    int tid = threadIdx.x;
    int node0 = blockIdx.x * 16;
    int nl = tid >> 4;
    int node = node0 + nl;
    int c8 = (tid & 15) * 8;
    int beg = row_ptr[node], end = row_ptr[node + 1];
    float a0[8] = {0.f, 0.f, 0.f, 0.f, 0.f, 0.f, 0.f, 0.f};
    float a1[8] = {0.f, 0.f, 0.f, 0.f, 0.f, 0.f, 0.f, 0.f};
    int j = beg;
    for (; j + 3 < end; j += 4) {
        int u0 = csr[j].x, u1 = csr[j + 1].x, u2 = csr[j + 2].x, u3 = csr[j + 3].x;
        uint4 v0 = *(const uint4*)(xm + (size_t)u0 * HD + c8);
        uint4 v1 = *(const uint4*)(xm + (size_t)u1 * HD + c8);
        uint4 v2 = *(const uint4*)(xm + (size_t)u2 * HD + c8);
        uint4 v3 = *(const uint4*)(xm + (size_t)u3 * HD + c8);
        accum8(a0, v0);
        accum8(a1, v1);
        accum8(a0, v2);
        accum8(a1, v3);
    }
    for (; j < end; ++j) {
        uint4 v = *(const uint4*)(xm + (size_t)csr[j].x * HD + c8);
        accum8(a0, v);
    }
    accum8(a0, *(const uint4*)(selfb + (size_t)node * HD + c8));
#pragma unroll
    for (int i = 0; i < 8; ++i) hloc[nl][c8 + i] = fmaxf(a0[i] + a1[i], 0.f);
    __syncthreads();
    if (tid < HD) {
        int f = tid;
        float run = 0.f;
        int gprev = batch[node0];
        for (int r = 0; r < 16; ++r) {
            int g = batch[node0 + r];
            if (g != gprev) {
                atomicAdd(&pooled[gprev * HD + f], run);
                run = 0.f;
                gprev = g;
            }
            run += hloc[r][f];
        }
        atomicAdd(&pooled[gprev * HD + f], run);
    }
}

// ---------------- fusion head (reads completed pooled sums) ----------------

__global__ void head_kernel(const float* __restrict__ pooled, const int* __restrict__ batch,
                            const float* __restrict__ lf, const float* __restrict__ pfe,
                            const float* __restrict__ Wl, const float* __restrict__ bl,
                            const float* __restrict__ Wp, const float* __restrict__ bp,
                            const float* __restrict__ Wf, const float* __restrict__ bfv,
                            const float* __restrict__ Wo, const float* __restrict__ bo,
                            float* __restrict__ out) {
    __shared__ float cat[3 * HD];
    __shared__ float red[HD];
    int g = blockIdx.x, j = threadIdx.x;
    int lo = 0, hi = NN;
    while (lo < hi) { int m = (lo + hi) >> 1; if (batch[m] < g) lo = m + 1; else hi = m; }
    int s0 = lo;
    lo = s0; hi = NN;
    while (lo < hi) { int m = (lo + hi) >> 1; if (batch[m] < g + 1) lo = m + 1; else hi = m; }
    float cntf = (float)(lo - s0);
    cat[j] = pooled[(size_t)g * HD + j] / fmaxf(cntf, 1.f);
    float s = bl[j];
    for (int k = 0; k < FL; ++k) s += lf[g * FL + k] * Wl[k * HD + j];
    cat[HD + j] = s;
    s = bp[j];
    for (int k = 0; k < FPOC; ++k) s += pfe[g * FPOC + k] * Wp[k * HD + j];
    cat[2 * HD + j] = s;
    __syncthreads();
    float fj = bfv[j];
    for (int k = 0; k < 3 * HD; ++k) fj += cat[k] * Wf[k * HD + j];
    red[j] = fj * Wo[j];
    __syncthreads();
    for (int off = 64; off > 0; off >>= 1) {
        if (j < off) red[j] += red[j + off];
        __syncthreads();
    }
    if (j == 0) out[g] = red[0] + bo[0];
}

// ---------------- launch ----------------

extern "C" void kernel_launch(void* const* d_in, const int* in_sizes, int n_in,
                              void* d_out, int out_size, void* d_ws, size_t ws_size,
                              hipStream_t stream) {
    const float* x       = (const float*)d_in[0];
    const int*   ei      = (const int*)d_in[1];
    const float* ea      = (const float*)d_in[2];
    const int*   batch   = (const int*)d_in[3];
    const float* lf      = (const float*)d_in[4];
    const float* pfe     = (const float*)d_in[5];
    const float* W1_msg  = (const float*)d_in[6];
    const float* b1_msg  = (const float*)d_in[7];
    const float* W1_edge = (const float*)d_in[8];
    const float* b1_edge = (const float*)d_in[9];
    const float* W1_self = (const float*)d_in[10];
    const float* b1_self = (const float*)d_in[11];
    const float* Wk_msg  = (const float*)d_in[12];
    const float* bk_msg  = (const float*)d_in[13];
    const float* Wk_edge = (const float*)d_in[14];
    const float* bk_edge = (const float*)d_in[15];
    const float* Wl      = (const float*)d_in[16];
    const float* bl      = (const float*)d_in[17];
    const float* Wp      = (const float*)d_in[18];
    const float* bp      = (const float*)d_in[19];
    const float* Wf      = (const float*)d_in[20];
    const float* bfv     = (const float*)d_in[21];
    const float* Wo      = (const float*)d_in[22];
    const float* bo      = (const float*)d_in[23];

    char* wsp = (char*)d_ws;
    size_t off = 0;
    auto carve = [&](size_t bytes) -> void* {
        char* p = wsp + off;
        off += (bytes + 255) & ~(size_t)255;
        return (void*)p;
    };
    int*      cnt     = (int*)carve((size_t)NN * 4);
    float*    pooled  = (float*)carve((size_t)NG * HD * 4);
    int*      row_ptr = (int*)carve((size_t)(NN + 1) * 4);
    int2*     csr     = (int2*)carve((size_t)NE * 8);
    ushort_t* segaug  = (ushort_t*)carve((size_t)NN * 32 * 2);
    ushort_t* pack    = (ushort_t*)carve((size_t)81920 * 2);
    ushort_t* bufC    = (ushort_t*)carve((size_t)NN * HD * 2);  // msg ping
    ushort_t* bufD    = (ushort_t*)carve((size_t)NN * HD * 2);  // msg pong
    ushort_t* bufS    = (ushort_t*)carve((size_t)NN * HD * 2);  // S ping
    ushort_t* bufT    = (ushort_t*)carve((size_t)NN * HD * 2);  // S pong
    int*      bsum    = (int*)carve((size_t)256 * 4);
    int*      bpre    = (int*)carve((size_t)256 * 4);

    const int NBLK = (NN + 255) / 256;

    // clear cnt..end-of-pooled using the true pointer delta (round-10 fix:
    // carve's 256B alignment made the old (NN+NG*HD)*4 size miss pooled's
    // last 192 bytes -> poisoned accumulator tail)
    size_t clr = (size_t)((char*)(pooled + NG * HD) - (char*)cnt);
    hipMemsetAsync(cnt, 0, clr, stream);

    count_kernel<<<(NE + 255) / 256, 256, 0, stream>>>(ei, cnt);
    bsum_kernel<<<NBLK, 256, 0, stream>>>(cnt, bsum);
    bscan_kernel<<<1, 256, 0, stream>>>(bsum, bpre, NBLK);
    rowptr_kernel<<<NBLK, 256, 0, stream>>>(cnt, bpre, row_ptr);
    fill_kernel<<<(NE + 255) / 256, 256, 0, stream>>>(ei, row_ptr, cnt, csr);
    sege_kernel<<<(NN + 3) / 4, 256, 0, stream>>>(row_ptr, csr, ea, segaug);
    repack_kernel<<<dim3(8, 9), 256, 0, stream>>>(W1_msg, W1_self, W1_edge, b1_msg,
                                                  b1_edge, b1_self, Wk_msg, Wk_edge,
                                                  bk_msg, bk_edge, pack);

    // conv1: msg1 -> bufC, S1 = x@W1_self + edge-term -> bufS
    gemm_mfma_conv1<<<dim3((NN + 63) / 64), 256, 0, stream>>>(x, segaug, pack, bufC,
                                                              bufS, NN);
    // fused layers (h stays on-chip)
    fused_agg_gemm<<<NN / 16, 256, 0, stream>>>(row_ptr, csr, bufC, bufS, segaug,
                                                pack + 20480, pack + 69632, bufD, bufT);
    fused_agg_gemm<<<NN / 16, 256, 0, stream>>>(row_ptr, csr, bufD, bufT, segaug,
                                                pack + 20480 + 16384, pack + 69632 + 4096,
                                                bufC, bufS);
    fused_agg_gemm<<<NN / 16, 256, 0, stream>>>(row_ptr, csr, bufC, bufS, segaug,
                                                pack + 20480 + 32768, pack + 69632 + 8192,
                                                bufD, bufT);
    // final agg fused with mean-pool accumulation (h4 never hits global)
    agg_pool_kernel<<<NN / 16, 256, 0, stream>>>(row_ptr, csr, bufD, bufT, batch, pooled);

    head_kernel<<<NG, HD, 0, stream>>>(pooled, batch, lf, pfe, Wl, bl, Wp, bp, Wf, bfv,
                                       Wo, bo, (float*)d_out);
}